// Round 10
// baseline (234.641 us; speedup 1.0000x reference)
//
#include <hip/hip_runtime.h>

#define NN 100000
#define NE 1600000

#define BSH 7
#define BNODES 128               // nodes per bucket
#define NBUCK 782                // ceil(NN / 128)
#define NBUCKP 784
#define CAP 2560                 // words per bucket region (exp 2048, +11 sigma)
#define ECH 2048                 // edges per chunk
#define NCHK 782                 // ceil(NE / ECH)

typedef _Float16 half8v __attribute__((ext_vector_type(8)));
typedef _Float16 half4v __attribute__((ext_vector_type(4)));
typedef float f32x4 __attribute__((ext_vector_type(4)));

// ---------------- bucket partition (no global atomics) ----------------

__global__ __launch_bounds__(256) void k_count(const int* __restrict__ dst,
                                               int* __restrict__ histT) {
    __shared__ int h[NBUCKP];
    const int t = threadIdx.x;
    for (int b = t; b < NBUCKP; b += 256) h[b] = 0;
    __syncthreads();
    const long long e0 = (long long)blockIdx.x * ECH;
#pragma unroll
    for (int i = 0; i < ECH / 256; i++) {
        long long e = e0 + i * 256 + t;
        if (e < NE) atomicAdd(&h[dst[e] >> BSH], 1);
    }
    __syncthreads();
    for (int b = t; b < NBUCK; b += 256) histT[(long long)b * NCHK + blockIdx.x] = h[b];
}

__global__ __launch_bounds__(256) void k_scanb(int* __restrict__ histT,
                                               int* __restrict__ cntb) {
    __shared__ int s[256];
    const int b = blockIdx.x, t = threadIdx.x;
    int* row = histT + (long long)b * NCHK;
    int v[4];
    int sum = 0;
#pragma unroll
    for (int j = 0; j < 4; j++) {
        int idx = t * 4 + j;
        v[j] = (idx < NCHK) ? row[idx] : 0;
        sum += v[j];
    }
    s[t] = sum;
    __syncthreads();
    for (int off = 1; off < 256; off <<= 1) {
        int u = (t >= off) ? s[t - off] : 0;
        __syncthreads();
        s[t] += u;
        __syncthreads();
    }
    int run = s[t] - sum;
#pragma unroll
    for (int j = 0; j < 4; j++) {
        int idx = t * 4 + j;
        if (idx < NCHK) row[idx] = run;
        run += v[j];
    }
    if (t == 255) cntb[b] = s[255];
}

__global__ __launch_bounds__(256) void k_part(const int* __restrict__ src,
                                              const int* __restrict__ dst,
                                              const int* __restrict__ histT,
                                              int* __restrict__ data) {
    __shared__ int curs[NBUCKP];
    const int t = threadIdx.x, blk = blockIdx.x;
    for (int b = t; b < NBUCKP; b += 256)
        curs[b] = b * CAP + ((b < NBUCK) ? histT[(long long)b * NCHK + blk] : 0);
    __syncthreads();
    const long long e0 = (long long)blk * ECH;
#pragma unroll
    for (int i = 0; i < ECH / 256; i++) {
        long long e = e0 + i * 256 + t;
        if (e < NE) {
            int d = dst[e], sv = src[e];
            int b = d >> BSH;
            int p = atomicAdd(&curs[b], 1);
            data[p] = (sv << BSH) | (d & (BNODES - 1));
        }
    }
}

// per-bucket LDS counting sort -> dst-ordered col[] + beg/end + dinv.
__global__ __launch_bounds__(256) void k_sortb(const int* __restrict__ data,
                                               const int* __restrict__ cntb,
                                               int* __restrict__ col,
                                               int* __restrict__ begp,
                                               int* __restrict__ endp,
                                               float* __restrict__ dinv) {
    __shared__ int hist[BNODES];
    __shared__ int scn[BNODES];
    __shared__ int curs[BNODES];
    const int b = blockIdx.x, t = threadIdx.x;
    if (t < BNODES) hist[t] = 0;
    __syncthreads();
    const int cnt = cntb[b];
    const int* wp = data + b * CAP;
    for (int e = t; e < cnt; e += 256) atomicAdd(&hist[wp[e] & (BNODES - 1)], 1);
    __syncthreads();
    if (t < BNODES) scn[t] = hist[t];
    __syncthreads();
    for (int off = 1; off < BNODES; off <<= 1) {
        int v = (t < BNODES && t >= off) ? scn[t - off] : 0;
        __syncthreads();
        if (t < BNODES) scn[t] += v;
        __syncthreads();
    }
    if (t < BNODES) {
        int beg = scn[t] - hist[t];
        curs[t] = beg;
        int node = (b << BSH) + t;
        if (node < NN) {
            begp[node] = b * CAP + beg;
            endp[node] = b * CAP + scn[t];
            dinv[node] = rsqrtf((float)(hist[t] + 1));
        }
    }
    __syncthreads();
    for (int e = t; e < cnt; e += 256) {
        int w = wp[e];
        int p = atomicAdd(&curs[w & (BNODES - 1)], 1);
        col[b * CAP + p] = w >> BSH;
    }
}

// ---------------- W -> fp16 B-fragment layout (all three, one launch) ----------------
// Wf[((kt*(N/16)+nt)*64 + l)*8 + j] = W[(kt*32 + (l>>4)*8 + j)*N + nt*16 + (l&15)]

__device__ __forceinline__ void wfrag_one(const float* __restrict__ W,
                                          _Float16* __restrict__ Wf, int idx, int N) {
    int j = idx & 7;
    int l = (idx >> 3) & 63;
    int f = idx >> 9;
    int nt = f % (N / 16);
    int kt = f / (N / 16);
    int k = kt * 32 + (l >> 4) * 8 + j;
    int c = nt * 16 + (l & 15);
    Wf[idx] = (_Float16)W[k * N + c];
}

__global__ __launch_bounds__(256) void k_wfrag_all(const float* __restrict__ W1,
                                                   const float* __restrict__ W2,
                                                   const float* __restrict__ W3,
                                                   _Float16* __restrict__ Wf1,
                                                   _Float16* __restrict__ Wf2,
                                                   _Float16* __restrict__ Wf3) {
    int idx = blockIdx.x * 256 + threadIdx.x;
    if (idx < 65536) wfrag_one(W1, Wf1, idx, 256);
    else if (idx < 131072) wfrag_one(W2, Wf2, idx - 65536, 256);
    else if (idx < 139264) wfrag_one(W3, Wf3, idx - 131072, 32);
}

// ---------------- wave-independent MLP: 16 nodes/wave, ZERO barriers ----------------
// Swapped mfma: h^T[tile ct] = mfma(Wf_frag (A: c=lane&15, k contig),
//                                   h_frag  (B: node=lane&15, k contig)).
// Output: node = lane&15, channel = 16*ct + 4*(lane>>4) + r  -> regroup to the
// next layer's fragment layout via a wave-PRIVATE 8KB LDS bounce (no barrier;
// same-wave DS ops are in-order).

__global__ __launch_bounds__(256) void k_mlpw(const float* __restrict__ x,
                                              const _Float16* __restrict__ Wf1,
                                              const _Float16* __restrict__ Wf2,
                                              const _Float16* __restrict__ Wf3,
                                              const float* __restrict__ b1,
                                              const float* __restrict__ b2,
                                              const float* __restrict__ b3,
                                              const float* __restrict__ dinv,
                                              float* __restrict__ h0,
                                              float* __restrict__ hs0) {
    __shared__ char lds[4 * 8192];  // 8KB private per wave
    const int t = threadIdx.x;
    const int lane = t & 63;
    const int i = lane & 15;      // node index within wave tile
    const int G = lane >> 4;      // 4-lane-group (channel quad / k-group)
    const int wv = t >> 6;
    const int wid = blockIdx.x * 4 + wv;
    if (wid >= NN / 16) return;
    const long long node0 = (long long)wid * 16;
    char* myl = lds + wv * 8192;
    const int swz = (i & 7) << 4;

    const half8v* W1f = reinterpret_cast<const half8v*>(Wf1);
    const half8v* W2f = reinterpret_cast<const half8v*>(Wf2);
    const half8v* W3f = reinterpret_cast<const half8v*>(Wf3);

    f32x4 acc[16];

    // ---- GEMM1 (swapped): x fragments direct from global ----
#pragma unroll
    for (int ct = 0; ct < 16; ct++) acc[ct] = (f32x4)0.f;
    {
        const float* xrow = x + (node0 + i) * 256 + G * 8;
#pragma unroll
        for (int kt = 0; kt < 8; kt++) {
            float4 lo = *reinterpret_cast<const float4*>(xrow + kt * 32);
            float4 hi = *reinterpret_cast<const float4*>(xrow + kt * 32 + 4);
            half8v xa;
            xa[0] = (_Float16)lo.x; xa[1] = (_Float16)lo.y;
            xa[2] = (_Float16)lo.z; xa[3] = (_Float16)lo.w;
            xa[4] = (_Float16)hi.x; xa[5] = (_Float16)hi.y;
            xa[6] = (_Float16)hi.z; xa[7] = (_Float16)hi.w;
#pragma unroll
            for (int ct = 0; ct < 16; ct++)
                acc[ct] = __builtin_amdgcn_mfma_f32_16x16x32_f16(W1f[(kt * 16 + ct) * 64 + lane], xa, acc[ct], 0, 0, 0);
        }
    }

    // ---- transition 1: bias+relu, pack fp16, private-LDS regroup ----
#pragma unroll
    for (int ct = 0; ct < 16; ct++) {
        float4 bv = *reinterpret_cast<const float4*>(b1 + ct * 16 + G * 4);
        half4v hv;
        hv[0] = (_Float16)fmaxf(acc[ct][0] + bv.x, 0.f);
        hv[1] = (_Float16)fmaxf(acc[ct][1] + bv.y, 0.f);
        hv[2] = (_Float16)fmaxf(acc[ct][2] + bv.z, 0.f);
        hv[3] = (_Float16)fmaxf(acc[ct][3] + bv.w, 0.f);
        int bo = (i * 512 + ct * 32 + G * 8) ^ swz;
        *reinterpret_cast<half4v*>(myl + bo) = hv;
    }
    half8v af[8];
#pragma unroll
    for (int kt = 0; kt < 8; kt++) {
        int bo = (i * 512 + kt * 64 + G * 16) ^ swz;
        af[kt] = *reinterpret_cast<const half8v*>(myl + bo);
    }

    // ---- GEMM2 (swapped) ----
#pragma unroll
    for (int ct = 0; ct < 16; ct++) acc[ct] = (f32x4)0.f;
#pragma unroll
    for (int kt = 0; kt < 8; kt++)
#pragma unroll
        for (int ct = 0; ct < 16; ct++)
            acc[ct] = __builtin_amdgcn_mfma_f32_16x16x32_f16(W2f[(kt * 16 + ct) * 64 + lane], af[kt], acc[ct], 0, 0, 0);

    // ---- transition 2 ----
#pragma unroll
    for (int ct = 0; ct < 16; ct++) {
        float4 bv = *reinterpret_cast<const float4*>(b2 + ct * 16 + G * 4);
        half4v hv;
        hv[0] = (_Float16)fmaxf(acc[ct][0] + bv.x, 0.f);
        hv[1] = (_Float16)fmaxf(acc[ct][1] + bv.y, 0.f);
        hv[2] = (_Float16)fmaxf(acc[ct][2] + bv.z, 0.f);
        hv[3] = (_Float16)fmaxf(acc[ct][3] + bv.w, 0.f);
        int bo = (i * 512 + ct * 32 + G * 8) ^ swz;
        *reinterpret_cast<half4v*>(myl + bo) = hv;
    }
#pragma unroll
    for (int kt = 0; kt < 8; kt++) {
        int bo = (i * 512 + kt * 64 + G * 16) ^ swz;
        af[kt] = *reinterpret_cast<const half8v*>(myl + bo);
    }

    // ---- GEMM3 (swapped): 2 channel tiles ----
    f32x4 a3[2];
    a3[0] = (f32x4)0.f; a3[1] = (f32x4)0.f;
#pragma unroll
    for (int kt = 0; kt < 8; kt++) {
#pragma unroll
        for (int ct = 0; ct < 2; ct++)
            a3[ct] = __builtin_amdgcn_mfma_f32_16x16x32_f16(W3f[(kt * 2 + ct) * 64 + lane], af[kt], a3[ct], 0, 0, 0);
    }

    // ---- epilogue: h0 / hs0 (float4 stores) ----
    const float dd = dinv[node0 + i];
#pragma unroll
    for (int ct = 0; ct < 2; ct++) {
        float4 bv = *reinterpret_cast<const float4*>(b3 + ct * 16 + G * 4);
        float4 o;
        o.x = a3[ct][0] + bv.x; o.y = a3[ct][1] + bv.y;
        o.z = a3[ct][2] + bv.z; o.w = a3[ct][3] + bv.w;
        size_t off = (size_t)(node0 + i) * 32 + ct * 16 + G * 4;
        *reinterpret_cast<float4*>(h0 + off) = o;
        float4 s;
        s.x = dd * o.x; s.y = dd * o.y; s.z = dd * o.z; s.w = dd * o.w;
        *reinterpret_cast<float4*>(hs0 + off) = s;
    }
}

// ---------------- fused APPNP step (per-node gather, 4-way unrolled) ----------------

template<bool FINAL>
__global__ __launch_bounds__(256) void k_appnp(const int* __restrict__ begp,
                                               const int* __restrict__ endp,
                                               const int* __restrict__ col,
                                               const float* __restrict__ dinv,
                                               const float* __restrict__ hs,
                                               const float* __restrict__ h0,
                                               float* __restrict__ outp) {
    int node = blockIdx.x * 8 + (threadIdx.x >> 5);
    if (node >= NN) return;
    int c = threadIdx.x & 31;
    int e = begp[node];
    const int end = endp[node];
    float a0 = 0.f, a1 = 0.f, a2 = 0.f, a3 = 0.f;
    for (; e + 4 <= end; e += 4) {
        int s0 = col[e], s1 = col[e + 1], s2 = col[e + 2], s3 = col[e + 3];
        a0 += hs[(size_t)s0 * 32 + c];
        a1 += hs[(size_t)s1 * 32 + c];
        a2 += hs[(size_t)s2 * 32 + c];
        a3 += hs[(size_t)s3 * 32 + c];
    }
    for (; e < end; e++) a0 += hs[(size_t)col[e] * 32 + c];
    size_t off = (size_t)node * 32 + c;
    float dd = dinv[node];
    float hnew = 0.9f * dd * (((a0 + a1) + (a2 + a3)) + hs[off]) + 0.1f * h0[off];
    outp[off] = FINAL ? hnew : dd * hnew;
}

// ---------------- launch ----------------

extern "C" void kernel_launch(void* const* d_in, const int* in_sizes, int n_in,
                              void* d_out, int out_size, void* d_ws, size_t ws_size,
                              hipStream_t stream) {
    const float* x     = (const float*)d_in[0];
    const int*   ei    = (const int*)d_in[1];
    const float* W_in  = (const float*)d_in[2];
    const float* b_in  = (const float*)d_in[3];
    const float* W_h   = (const float*)d_in[4];
    const float* b_h   = (const float*)d_in[5];
    const float* W_out = (const float*)d_in[6];
    const float* b_out = (const float*)d_in[7];
    float* out = (float*)d_out;

    const int* srcv = ei;
    const int* dstv = ei + NE;

    char* ws = (char*)d_ws;
    float* h0      = (float*)ws;                                 // NN*32 f32
    float* hs0     = h0 + (size_t)NN * 32;                       // NN*32
    float* hs1     = hs0 + (size_t)NN * 32;                      // NN*32
    float* dinv    = hs1 + (size_t)NN * 32;                      // NN
    _Float16* Wf_in  = (_Float16*)(dinv + NN);                   // 256*256
    _Float16* Wf_h   = Wf_in + 256 * 256;                        // 256*256
    _Float16* Wf_out = Wf_h + 256 * 256;                         // 256*32
    int* histT = (int*)(Wf_out + 256 * 32);                      // NBUCK*NCHK
    int* cntb  = histT + (size_t)NBUCK * NCHK;                   // NBUCKP
    int* data  = cntb + NBUCKP;                                  // NBUCKP*CAP
    int* col   = data + (size_t)NBUCKP * CAP;                    // NBUCKP*CAP
    int* begp  = col + (size_t)NBUCKP * CAP;                     // NN
    int* endp  = begp + NN;                                      // NN

    // --- bucket partition + local counting sort -> CSR + dinv ---
    k_count<<<NCHK, 256, 0, stream>>>(dstv, histT);
    k_scanb<<<NBUCK, 256, 0, stream>>>(histT, cntb);
    k_part<<<NCHK, 256, 0, stream>>>(srcv, dstv, histT, data);
    k_sortb<<<NBUCK, 256, 0, stream>>>(data, cntb, col, begp, endp, dinv);

    // --- W fragments (one launch) ---
    k_wfrag_all<<<544, 256, 0, stream>>>(W_in, W_h, W_out, Wf_in, Wf_h, Wf_out);

    // --- wave-independent MLP (x -> h0, hs0), 16 nodes/wave, no barriers ---
    k_mlpw<<<(NN / 16 + 3) / 4, 256, 0, stream>>>(x, Wf_in, Wf_h, Wf_out,
                                                  b_in, b_h, b_out, dinv, h0, hs0);

    // --- APPNP: K = 2 ---
    k_appnp<false><<<(NN + 7) / 8, 256, 0, stream>>>(begp, endp, col, dinv, hs0, h0, hs1);
    k_appnp<true ><<<(NN + 7) / 8, 256, 0, stream>>>(begp, endp, col, dinv, hs1, h0, out);
}

// Round 11
// 219.719 us; speedup vs baseline: 1.0679x; 1.0679x over previous
//
#include <hip/hip_runtime.h>

#define NN 100000
#define NE 1600000
#define NTILE 3125   // NN / 32

#define BSH 7
#define BNODES 128               // nodes per bucket
#define NBUCK 782                // ceil(NN / 128)
#define NBUCKP 784
#define CAP 2560                 // words per bucket region (exp 2048, +11 sigma)
#define ECH 2048                 // edges per chunk
#define NCHK 782                 // ceil(NE / ECH)

typedef _Float16 half8v __attribute__((ext_vector_type(8)));
typedef _Float16 half4v __attribute__((ext_vector_type(4)));
typedef float f32x4 __attribute__((ext_vector_type(4)));

// ---------------- bucket partition (no global atomics) ----------------

__global__ __launch_bounds__(256) void k_count(const int* __restrict__ dst,
                                               int* __restrict__ histT) {
    __shared__ int h[NBUCKP];
    const int t = threadIdx.x;
    for (int b = t; b < NBUCKP; b += 256) h[b] = 0;
    __syncthreads();
    const long long e0 = (long long)blockIdx.x * ECH;
#pragma unroll
    for (int i = 0; i < ECH / 256; i++) {
        long long e = e0 + i * 256 + t;
        if (e < NE) atomicAdd(&h[dst[e] >> BSH], 1);
    }
    __syncthreads();
    for (int b = t; b < NBUCK; b += 256) histT[(long long)b * NCHK + blockIdx.x] = h[b];
}

__global__ __launch_bounds__(256) void k_scanb(int* __restrict__ histT,
                                               int* __restrict__ cntb) {
    __shared__ int s[256];
    const int b = blockIdx.x, t = threadIdx.x;
    int* row = histT + (long long)b * NCHK;
    int v[4];
    int sum = 0;
#pragma unroll
    for (int j = 0; j < 4; j++) {
        int idx = t * 4 + j;
        v[j] = (idx < NCHK) ? row[idx] : 0;
        sum += v[j];
    }
    s[t] = sum;
    __syncthreads();
    for (int off = 1; off < 256; off <<= 1) {
        int u = (t >= off) ? s[t - off] : 0;
        __syncthreads();
        s[t] += u;
        __syncthreads();
    }
    int run = s[t] - sum;
#pragma unroll
    for (int j = 0; j < 4; j++) {
        int idx = t * 4 + j;
        if (idx < NCHK) row[idx] = run;
        run += v[j];
    }
    if (t == 255) cntb[b] = s[255];
}

__global__ __launch_bounds__(256) void k_part(const int* __restrict__ src,
                                              const int* __restrict__ dst,
                                              const int* __restrict__ histT,
                                              int* __restrict__ data) {
    __shared__ int curs[NBUCKP];
    const int t = threadIdx.x, blk = blockIdx.x;
    for (int b = t; b < NBUCKP; b += 256)
        curs[b] = b * CAP + ((b < NBUCK) ? histT[(long long)b * NCHK + blk] : 0);
    __syncthreads();
    const long long e0 = (long long)blk * ECH;
#pragma unroll
    for (int i = 0; i < ECH / 256; i++) {
        long long e = e0 + i * 256 + t;
        if (e < NE) {
            int d = dst[e], sv = src[e];
            int b = d >> BSH;
            int p = atomicAdd(&curs[b], 1);
            data[p] = (sv << BSH) | (d & (BNODES - 1));
        }
    }
}

// per-bucket LDS counting sort -> dst-ordered col[] + beg/end + dinv.
__global__ __launch_bounds__(256) void k_sortb(const int* __restrict__ data,
                                               const int* __restrict__ cntb,
                                               int* __restrict__ col,
                                               int* __restrict__ begp,
                                               int* __restrict__ endp,
                                               float* __restrict__ dinv) {
    __shared__ int hist[BNODES];
    __shared__ int scn[BNODES];
    __shared__ int curs[BNODES];
    const int b = blockIdx.x, t = threadIdx.x;
    if (t < BNODES) hist[t] = 0;
    __syncthreads();
    const int cnt = cntb[b];
    const int* wp = data + b * CAP;
    for (int e = t; e < cnt; e += 256) atomicAdd(&hist[wp[e] & (BNODES - 1)], 1);
    __syncthreads();
    if (t < BNODES) scn[t] = hist[t];
    __syncthreads();
    for (int off = 1; off < BNODES; off <<= 1) {
        int v = (t < BNODES && t >= off) ? scn[t - off] : 0;
        __syncthreads();
        if (t < BNODES) scn[t] += v;
        __syncthreads();
    }
    if (t < BNODES) {
        int beg = scn[t] - hist[t];
        curs[t] = beg;
        int node = (b << BSH) + t;
        if (node < NN) {
            begp[node] = b * CAP + beg;
            endp[node] = b * CAP + scn[t];
            dinv[node] = rsqrtf((float)(hist[t] + 1));
        }
    }
    __syncthreads();
    for (int e = t; e < cnt; e += 256) {
        int w = wp[e];
        int p = atomicAdd(&curs[w & (BNODES - 1)], 1);
        col[b * CAP + p] = w >> BSH;
    }
}

// ---------------- W -> fp16 B-fragment layout (all three, one launch) ----------------
// Wf[((kt*(N/16)+nt)*64 + l)*8 + j] = W[(kt*32 + (l>>4)*8 + j)*N + nt*16 + (l&15)]

__device__ __forceinline__ void wfrag_one(const float* __restrict__ W,
                                          _Float16* __restrict__ Wf, int idx, int N) {
    int j = idx & 7;
    int l = (idx >> 3) & 63;
    int f = idx >> 9;
    int nt = f % (N / 16);
    int kt = f / (N / 16);
    int k = kt * 32 + (l >> 4) * 8 + j;
    int c = nt * 16 + (l & 15);
    Wf[idx] = (_Float16)W[k * N + c];
}

__global__ __launch_bounds__(256) void k_wfrag_all(const float* __restrict__ W1,
                                                   const float* __restrict__ W2,
                                                   const float* __restrict__ W3,
                                                   _Float16* __restrict__ Wf1,
                                                   _Float16* __restrict__ Wf2,
                                                   _Float16* __restrict__ Wf3) {
    int idx = blockIdx.x * 256 + threadIdx.x;
    if (idx < 65536) wfrag_one(W1, Wf1, idx, 256);
    else if (idx < 131072) wfrag_one(W2, Wf2, idx - 65536, 256);
    else if (idx < 139264) wfrag_one(W3, Wf3, idx - 131072, 32);
}

// ---------------- Layer 1: x -> h1 (fp16 row-major), W1 in REGISTERS ----------------
// 4 waves; wave w owns cols [64w, 64w+64) -> 32 W-fragments resident in VGPRs,
// loaded ONCE. Persistent grid-stride over 32-row tiles. Two 16KB LDS buffers
// alternate per tile; 3 barriers/tile.

__global__ __launch_bounds__(256) void k_lay1(const float* __restrict__ x,
                                              const _Float16* __restrict__ Wf1,
                                              const float* __restrict__ b1,
                                              _Float16* __restrict__ h1g) {
    __shared__ char lds[2][32 * 512];
    const int t = threadIdx.x;
    const int lane = t & 63;
    const int G = lane >> 4;
    const int w = t >> 6;

    // persistent W fragments + bias
    half8v wr[8][4];
    {
        const half8v* W1f = reinterpret_cast<const half8v*>(Wf1);
#pragma unroll
        for (int kt = 0; kt < 8; kt++)
#pragma unroll
            for (int nt = 0; nt < 4; nt++)
                wr[kt][nt] = W1f[(kt * 16 + w * 4 + nt) * 64 + lane];
    }
    float bvs[4];
#pragma unroll
    for (int nt = 0; nt < 4; nt++) bvs[nt] = b1[w * 64 + nt * 16 + (lane & 15)];

    int pp = 0;
    for (int T = blockIdx.x; T < NTILE; T += gridDim.x, pp ^= 1) {
        char* buf = lds[pp];
        // stage x tile fp32 -> fp16 swizzled (coalesced float4)
        const float4* A4 = reinterpret_cast<const float4*>(x + (size_t)T * 32 * 256);
        for (int i = t; i < 2048; i += 256) {
            int r = i >> 6, c4 = i & 63;
            float4 v = A4[i];
            half4v hv;
            hv[0] = (_Float16)v.x; hv[1] = (_Float16)v.y;
            hv[2] = (_Float16)v.z; hv[3] = (_Float16)v.w;
            int bo = (r * 512 + c4 * 8) ^ ((r & 7) << 4);
            *reinterpret_cast<half4v*>(buf + bo) = hv;
        }
        __syncthreads();

        f32x4 acc[2][4];
#pragma unroll
        for (int mt = 0; mt < 2; mt++)
#pragma unroll
            for (int nt = 0; nt < 4; nt++) acc[mt][nt] = (f32x4)0.f;
#pragma unroll
        for (int kt = 0; kt < 8; kt++) {
            half8v a[2];
#pragma unroll
            for (int mt = 0; mt < 2; mt++) {
                int row = mt * 16 + (lane & 15);
                int bo = (row * 512 + kt * 64 + (G << 4)) ^ ((row & 7) << 4);
                a[mt] = *reinterpret_cast<const half8v*>(buf + bo);
            }
#pragma unroll
            for (int mt = 0; mt < 2; mt++)
#pragma unroll
                for (int nt = 0; nt < 4; nt++)
                    acc[mt][nt] = __builtin_amdgcn_mfma_f32_16x16x32_f16(a[mt], wr[kt][nt], acc[mt][nt], 0, 0, 0);
        }
        __syncthreads();

        // epilogue: bias+relu -> fp16 into LDS (row-major swizzled)
#pragma unroll
        for (int mt = 0; mt < 2; mt++)
#pragma unroll
            for (int nt = 0; nt < 4; nt++) {
                int colc = w * 64 + nt * 16 + (lane & 15);
                float bb = bvs[nt];
#pragma unroll
                for (int r = 0; r < 4; r++) {
                    int row = mt * 16 + G * 4 + r;
                    float v = fmaxf(acc[mt][nt][r] + bb, 0.f);
                    int bo = (row * 512 + colc * 2) ^ ((row & 7) << 4);
                    *reinterpret_cast<_Float16*>(buf + bo) = (_Float16)v;
                }
            }
        __syncthreads();

        // copy LDS -> global h1 (coalesced 16B)
        for (int i = t; i < 1024; i += 256) {
            int r = i >> 5, c16 = i & 31;
            int bo = (r * 512 + c16 * 16) ^ ((r & 7) << 4);
            half8v v = *reinterpret_cast<const half8v*>(buf + bo);
            *reinterpret_cast<half8v*>(h1g + ((size_t)T * 32 + r) * 256 + c16 * 8) = v;
        }
        // next tile stages the other buffer; no barrier needed here
    }
}

// ---------------- Layers 2+3: h1 -> h0, hs0; W2 in REGISTERS, h2 LDS-only ----------------

__global__ __launch_bounds__(256) void k_lay23(const _Float16* __restrict__ h1g,
                                               const _Float16* __restrict__ Wf2,
                                               const _Float16* __restrict__ Wf3,
                                               const float* __restrict__ b2,
                                               const float* __restrict__ b3,
                                               const float* __restrict__ dinv,
                                               float* __restrict__ h0,
                                               float* __restrict__ hs0) {
    __shared__ char lds[2][32 * 512];
    const int t = threadIdx.x;
    const int lane = t & 63;
    const int G = lane >> 4;
    const int w = t >> 6;

    half8v wr[8][4];
    {
        const half8v* W2f = reinterpret_cast<const half8v*>(Wf2);
#pragma unroll
        for (int kt = 0; kt < 8; kt++)
#pragma unroll
            for (int nt = 0; nt < 4; nt++)
                wr[kt][nt] = W2f[(kt * 16 + w * 4 + nt) * 64 + lane];
    }
    float bvs[4];
#pragma unroll
    for (int nt = 0; nt < 4; nt++) bvs[nt] = b2[w * 64 + nt * 16 + (lane & 15)];

    // g3 assignment: wave w -> mt3 = w>>1 (rows), ct3 = w&1 (cols)
    const int mt3 = w >> 1, ct3 = w & 1;
    const half8v* W3f = reinterpret_cast<const half8v*>(Wf3);
    const float bb3 = b3[ct3 * 16 + (lane & 15)];

    int pp = 0;
    for (int T = blockIdx.x; T < NTILE; T += gridDim.x, pp ^= 1) {
        char* buf = lds[pp];
        // stage h1 tile (fp16, coalesced 16B) -> swizzled LDS
        const half8v* A8 = reinterpret_cast<const half8v*>(h1g + (size_t)T * 32 * 256);
        for (int i = t; i < 1024; i += 256) {
            int r = i >> 5, c8 = i & 31;
            int bo = (r * 512 + c8 * 16) ^ ((r & 7) << 4);
            *reinterpret_cast<half8v*>(buf + bo) = A8[i];
        }
        __syncthreads();

        // GEMM2 (W2 regs)
        f32x4 acc[2][4];
#pragma unroll
        for (int mt = 0; mt < 2; mt++)
#pragma unroll
            for (int nt = 0; nt < 4; nt++) acc[mt][nt] = (f32x4)0.f;
#pragma unroll
        for (int kt = 0; kt < 8; kt++) {
            half8v a[2];
#pragma unroll
            for (int mt = 0; mt < 2; mt++) {
                int row = mt * 16 + (lane & 15);
                int bo = (row * 512 + kt * 64 + (G << 4)) ^ ((row & 7) << 4);
                a[mt] = *reinterpret_cast<const half8v*>(buf + bo);
            }
#pragma unroll
            for (int mt = 0; mt < 2; mt++)
#pragma unroll
                for (int nt = 0; nt < 4; nt++)
                    acc[mt][nt] = __builtin_amdgcn_mfma_f32_16x16x32_f16(a[mt], wr[kt][nt], acc[mt][nt], 0, 0, 0);
        }
        __syncthreads();

        // h2 -> LDS (row-major swizzled fp16)
#pragma unroll
        for (int mt = 0; mt < 2; mt++)
#pragma unroll
            for (int nt = 0; nt < 4; nt++) {
                int colc = w * 64 + nt * 16 + (lane & 15);
                float bb = bvs[nt];
#pragma unroll
                for (int r = 0; r < 4; r++) {
                    int row = mt * 16 + G * 4 + r;
                    float v = fmaxf(acc[mt][nt][r] + bb, 0.f);
                    int bo = (row * 512 + colc * 2) ^ ((row & 7) << 4);
                    *reinterpret_cast<_Float16*>(buf + bo) = (_Float16)v;
                }
            }
        __syncthreads();

        // GEMM3: wave computes rows [mt3*16,+16) x cols [ct3*16,+16)
        f32x4 a3 = (f32x4)0.f;
#pragma unroll
        for (int kt = 0; kt < 8; kt++) {
            int row = mt3 * 16 + (lane & 15);
            int bo = (row * 512 + kt * 64 + (G << 4)) ^ ((row & 7) << 4);
            half8v a = *reinterpret_cast<const half8v*>(buf + bo);
            half8v b = W3f[(kt * 2 + ct3) * 64 + lane];
            a3 = __builtin_amdgcn_mfma_f32_16x16x32_f16(a, b, a3, 0, 0, 0);
        }
        {
            int colc = ct3 * 16 + (lane & 15);
#pragma unroll
            for (int r = 0; r < 4; r++) {
                size_t row = (size_t)T * 32 + mt3 * 16 + G * 4 + r;
                float v = a3[r] + bb3;
                h0[row * 32 + colc] = v;
                hs0[row * 32 + colc] = dinv[row] * v;
            }
        }
        // next tile uses other buffer
    }
}

// ---------------- fused APPNP step (per-node gather, 4-way unrolled) ----------------

template<bool FINAL>
__global__ __launch_bounds__(256) void k_appnp(const int* __restrict__ begp,
                                               const int* __restrict__ endp,
                                               const int* __restrict__ col,
                                               const float* __restrict__ dinv,
                                               const float* __restrict__ hs,
                                               const float* __restrict__ h0,
                                               float* __restrict__ outp) {
    int node = blockIdx.x * 8 + (threadIdx.x >> 5);
    if (node >= NN) return;
    int c = threadIdx.x & 31;
    int e = begp[node];
    const int end = endp[node];
    float a0 = 0.f, a1 = 0.f, a2 = 0.f, a3 = 0.f;
    for (; e + 4 <= end; e += 4) {
        int s0 = col[e], s1 = col[e + 1], s2 = col[e + 2], s3 = col[e + 3];
        a0 += hs[(size_t)s0 * 32 + c];
        a1 += hs[(size_t)s1 * 32 + c];
        a2 += hs[(size_t)s2 * 32 + c];
        a3 += hs[(size_t)s3 * 32 + c];
    }
    for (; e < end; e++) a0 += hs[(size_t)col[e] * 32 + c];
    size_t off = (size_t)node * 32 + c;
    float dd = dinv[node];
    float hnew = 0.9f * dd * (((a0 + a1) + (a2 + a3)) + hs[off]) + 0.1f * h0[off];
    outp[off] = FINAL ? hnew : dd * hnew;
}

// ---------------- launch ----------------

extern "C" void kernel_launch(void* const* d_in, const int* in_sizes, int n_in,
                              void* d_out, int out_size, void* d_ws, size_t ws_size,
                              hipStream_t stream) {
    const float* x     = (const float*)d_in[0];
    const int*   ei    = (const int*)d_in[1];
    const float* W_in  = (const float*)d_in[2];
    const float* b_in  = (const float*)d_in[3];
    const float* W_h   = (const float*)d_in[4];
    const float* b_h   = (const float*)d_in[5];
    const float* W_out = (const float*)d_in[6];
    const float* b_out = (const float*)d_in[7];
    float* out = (float*)d_out;

    const int* srcv = ei;
    const int* dstv = ei + NE;

    char* ws = (char*)d_ws;
    float* h0      = (float*)ws;                                 // NN*32 f32
    float* hs0     = h0 + (size_t)NN * 32;                       // NN*32
    float* hs1     = hs0 + (size_t)NN * 32;                      // NN*32
    float* dinv    = hs1 + (size_t)NN * 32;                      // NN
    _Float16* Wf_in  = (_Float16*)(dinv + NN);                   // 256*256
    _Float16* Wf_h   = Wf_in + 256 * 256;                        // 256*256
    _Float16* Wf_out = Wf_h + 256 * 256;                         // 256*32
    _Float16* h1g    = Wf_out + 256 * 32;                        // NN*256 f16 (51.2MB)
    int* histT = (int*)(h1g + (size_t)NN * 256);                 // NBUCK*NCHK
    int* cntb  = histT + (size_t)NBUCK * NCHK;                   // NBUCKP
    int* data  = cntb + NBUCKP;                                  // NBUCKP*CAP
    int* col   = data + (size_t)NBUCKP * CAP;                    // NBUCKP*CAP
    int* begp  = col + (size_t)NBUCKP * CAP;                     // NN
    int* endp  = begp + NN;                                      // NN

    // --- bucket partition + local counting sort -> CSR + dinv ---
    k_count<<<NCHK, 256, 0, stream>>>(dstv, histT);
    k_scanb<<<NBUCK, 256, 0, stream>>>(histT, cntb);
    k_part<<<NCHK, 256, 0, stream>>>(srcv, dstv, histT, data);
    k_sortb<<<NBUCK, 256, 0, stream>>>(data, cntb, col, begp, endp, dinv);

    // --- W fragments (one launch) ---
    k_wfrag_all<<<544, 256, 0, stream>>>(W_in, W_h, W_out, Wf_in, Wf_h, Wf_out);

    // --- MLP: two persistent register-W kernels ---
    k_lay1<<<512, 256, 0, stream>>>(x, Wf_in, b_in, h1g);
    k_lay23<<<512, 256, 0, stream>>>(h1g, Wf_h, Wf_out, b_h, b_out, dinv, h0, hs0);

    // --- APPNP: K = 2 ---
    k_appnp<false><<<(NN + 7) / 8, 256, 0, stream>>>(begp, endp, col, dinv, hs0, h0, hs1);
    k_appnp<true ><<<(NN + 7) / 8, 256, 0, stream>>>(begp, endp, col, dinv, hs1, h0, out);
}

// Round 12
// 193.566 us; speedup vs baseline: 1.2122x; 1.1351x over previous
//
#include <hip/hip_runtime.h>

#define NN 100000
#define NE 1600000
#define NTILE 3125   // NN / 32

#define BSH 7
#define BNODES 128               // nodes per bucket
#define NBUCK 782                // ceil(NN / 128)
#define NBUCKP 784
#define CAP 2560                 // words per bucket region (exp 2048, +11 sigma)
#define ECH 2048                 // edges per chunk
#define NCHK 782                 // ceil(NE / ECH)

typedef _Float16 half8v __attribute__((ext_vector_type(8)));
typedef _Float16 half4v __attribute__((ext_vector_type(4)));
typedef float f32x4 __attribute__((ext_vector_type(4)));

// ---------------- bucket partition (no global atomics) ----------------

__global__ __launch_bounds__(256) void k_count(const int* __restrict__ dst,
                                               int* __restrict__ histT) {
    __shared__ int h[NBUCKP];
    const int t = threadIdx.x;
    for (int b = t; b < NBUCKP; b += 256) h[b] = 0;
    __syncthreads();
    const long long e0 = (long long)blockIdx.x * ECH;
#pragma unroll
    for (int i = 0; i < ECH / 256; i++) {
        long long e = e0 + i * 256 + t;
        if (e < NE) atomicAdd(&h[dst[e] >> BSH], 1);
    }
    __syncthreads();
    for (int b = t; b < NBUCK; b += 256) histT[(long long)b * NCHK + blockIdx.x] = h[b];
}

__global__ __launch_bounds__(256) void k_scanb(int* __restrict__ histT,
                                               int* __restrict__ cntb) {
    __shared__ int s[256];
    const int b = blockIdx.x, t = threadIdx.x;
    int* row = histT + (long long)b * NCHK;
    int v[4];
    int sum = 0;
#pragma unroll
    for (int j = 0; j < 4; j++) {
        int idx = t * 4 + j;
        v[j] = (idx < NCHK) ? row[idx] : 0;
        sum += v[j];
    }
    s[t] = sum;
    __syncthreads();
    for (int off = 1; off < 256; off <<= 1) {
        int u = (t >= off) ? s[t - off] : 0;
        __syncthreads();
        s[t] += u;
        __syncthreads();
    }
    int run = s[t] - sum;
#pragma unroll
    for (int j = 0; j < 4; j++) {
        int idx = t * 4 + j;
        if (idx < NCHK) row[idx] = run;
        run += v[j];
    }
    if (t == 255) cntb[b] = s[255];
}

__global__ __launch_bounds__(256) void k_part(const int* __restrict__ src,
                                              const int* __restrict__ dst,
                                              const int* __restrict__ histT,
                                              int* __restrict__ data) {
    __shared__ int curs[NBUCKP];
    const int t = threadIdx.x, blk = blockIdx.x;
    for (int b = t; b < NBUCKP; b += 256)
        curs[b] = b * CAP + ((b < NBUCK) ? histT[(long long)b * NCHK + blk] : 0);
    __syncthreads();
    const long long e0 = (long long)blk * ECH;
#pragma unroll
    for (int i = 0; i < ECH / 256; i++) {
        long long e = e0 + i * 256 + t;
        if (e < NE) {
            int d = dst[e], sv = src[e];
            int b = d >> BSH;
            int p = atomicAdd(&curs[b], 1);
            data[p] = (sv << BSH) | (d & (BNODES - 1));
        }
    }
}

// per-bucket LDS counting sort -> dst-ordered col[] + beg/end + dinv.
__global__ __launch_bounds__(256) void k_sortb(const int* __restrict__ data,
                                               const int* __restrict__ cntb,
                                               int* __restrict__ col,
                                               int* __restrict__ begp,
                                               int* __restrict__ endp,
                                               float* __restrict__ dinv) {
    __shared__ int hist[BNODES];
    __shared__ int scn[BNODES];
    __shared__ int curs[BNODES];
    const int b = blockIdx.x, t = threadIdx.x;
    if (t < BNODES) hist[t] = 0;
    __syncthreads();
    const int cnt = cntb[b];
    const int* wp = data + b * CAP;
    for (int e = t; e < cnt; e += 256) atomicAdd(&hist[wp[e] & (BNODES - 1)], 1);
    __syncthreads();
    if (t < BNODES) scn[t] = hist[t];
    __syncthreads();
    for (int off = 1; off < BNODES; off <<= 1) {
        int v = (t < BNODES && t >= off) ? scn[t - off] : 0;
        __syncthreads();
        if (t < BNODES) scn[t] += v;
        __syncthreads();
    }
    if (t < BNODES) {
        int beg = scn[t] - hist[t];
        curs[t] = beg;
        int node = (b << BSH) + t;
        if (node < NN) {
            begp[node] = b * CAP + beg;
            endp[node] = b * CAP + scn[t];
            dinv[node] = rsqrtf((float)(hist[t] + 1));
        }
    }
    __syncthreads();
    for (int e = t; e < cnt; e += 256) {
        int w = wp[e];
        int p = atomicAdd(&curs[w & (BNODES - 1)], 1);
        col[b * CAP + p] = w >> BSH;
    }
}

// ---------------- W -> fp16 B-fragment layout (all three, one launch) ----------------
// Wf[((kt*(N/16)+nt)*64 + l)*8 + j] = W[(kt*32 + (l>>4)*8 + j)*N + nt*16 + (l&15)]

__device__ __forceinline__ void wfrag_one(const float* __restrict__ W,
                                          _Float16* __restrict__ Wf, int idx, int N) {
    int j = idx & 7;
    int l = (idx >> 3) & 63;
    int f = idx >> 9;
    int nt = f % (N / 16);
    int kt = f / (N / 16);
    int k = kt * 32 + (l >> 4) * 8 + j;
    int c = nt * 16 + (l & 15);
    Wf[idx] = (_Float16)W[k * N + c];
}

__global__ __launch_bounds__(256) void k_wfrag_all(const float* __restrict__ W1,
                                                   const float* __restrict__ W2,
                                                   const float* __restrict__ W3,
                                                   _Float16* __restrict__ Wf1,
                                                   _Float16* __restrict__ Wf2,
                                                   _Float16* __restrict__ Wf3) {
    int idx = blockIdx.x * 256 + threadIdx.x;
    if (idx < 65536) wfrag_one(W1, Wf1, idx, 256);
    else if (idx < 131072) wfrag_one(W2, Wf2, idx - 65536, 256);
    else if (idx < 139264) wfrag_one(W3, Wf3, idx - 131072, 32);
}

// ---------------- Layer 1: x -> h1 (raw swizzled 16KB tile images) ----------------
// 3125 independent blocks x 512 threads (8 waves). Wave w owns cols
// [32w, 32w+32): W1 slice = 16 fragments = 64 VGPR, loaded once. Inner loop
// is pure ds_read+MFMA. h1 written as the verbatim swizzled LDS image.

__global__ __launch_bounds__(512) void k_lay1(const float* __restrict__ x,
                                              const _Float16* __restrict__ Wf1,
                                              const float* __restrict__ b1,
                                              _Float16* __restrict__ h1g) {
    __shared__ char buf[32 * 512];  // 16 KB
    const int t = threadIdx.x;
    const int lane = t & 63;
    const int G = lane >> 4;
    const int w = t >> 6;
    const int T = blockIdx.x;

    // W slice + bias (resident)
    half8v wr[8][2];
    {
        const half8v* W1f = reinterpret_cast<const half8v*>(Wf1);
#pragma unroll
        for (int kt = 0; kt < 8; kt++)
#pragma unroll
            for (int n2 = 0; n2 < 2; n2++)
                wr[kt][n2] = W1f[(kt * 16 + 2 * w + n2) * 64 + lane];
    }
    float bvs[2];
#pragma unroll
    for (int n2 = 0; n2 < 2; n2++) bvs[n2] = b1[w * 32 + n2 * 16 + (lane & 15)];

    // stage x tile fp32 -> fp16 swizzled (coalesced float4)
    {
        const float4* A4 = reinterpret_cast<const float4*>(x + (size_t)T * 32 * 256);
#pragma unroll
        for (int i = t; i < 2048; i += 512) {
            int r = i >> 6, c4 = i & 63;
            float4 v = A4[i];
            half4v hv;
            hv[0] = (_Float16)v.x; hv[1] = (_Float16)v.y;
            hv[2] = (_Float16)v.z; hv[3] = (_Float16)v.w;
            int bo = (r * 512 + c4 * 8) ^ ((r & 7) << 4);
            *reinterpret_cast<half4v*>(buf + bo) = hv;
        }
    }
    __syncthreads();

    // GEMM1: 32 rows x 32 cols per wave
    f32x4 acc[2][2];
#pragma unroll
    for (int mt = 0; mt < 2; mt++)
#pragma unroll
        for (int n2 = 0; n2 < 2; n2++) acc[mt][n2] = (f32x4)0.f;
#pragma unroll
    for (int kt = 0; kt < 8; kt++) {
        half8v a[2];
#pragma unroll
        for (int mt = 0; mt < 2; mt++) {
            int row = mt * 16 + (lane & 15);
            int bo = (row * 512 + kt * 64 + (G << 4)) ^ ((row & 7) << 4);
            a[mt] = *reinterpret_cast<const half8v*>(buf + bo);
        }
#pragma unroll
        for (int mt = 0; mt < 2; mt++)
#pragma unroll
            for (int n2 = 0; n2 < 2; n2++)
                acc[mt][n2] = __builtin_amdgcn_mfma_f32_16x16x32_f16(a[mt], wr[kt][n2], acc[mt][n2], 0, 0, 0);
    }
    __syncthreads();

    // bias+relu -> fp16 back into LDS (swizzled row-major image)
#pragma unroll
    for (int mt = 0; mt < 2; mt++)
#pragma unroll
        for (int n2 = 0; n2 < 2; n2++) {
            int colc = w * 32 + n2 * 16 + (lane & 15);
            float bb = bvs[n2];
#pragma unroll
            for (int r = 0; r < 4; r++) {
                int row = mt * 16 + G * 4 + r;
                float v = fmaxf(acc[mt][n2][r] + bb, 0.f);
                int bo = (row * 512 + colc * 2) ^ ((row & 7) << 4);
                *reinterpret_cast<_Float16*>(buf + bo) = (_Float16)v;
            }
        }
    __syncthreads();

    // dump raw image -> global (pure 16B memcpy)
    {
        half8v* dst = reinterpret_cast<half8v*>(h1g + (size_t)T * 8192);
        const half8v* srcp = reinterpret_cast<const half8v*>(buf);
#pragma unroll
        for (int i = t; i < 1024; i += 512) dst[i] = srcp[i];
    }
}

// ---------------- Layers 2+3: h1 image -> h0 (f32), hs0 (f16) ----------------

__global__ __launch_bounds__(512) void k_lay23(const _Float16* __restrict__ h1g,
                                               const _Float16* __restrict__ Wf2,
                                               const _Float16* __restrict__ Wf3,
                                               const float* __restrict__ b2,
                                               const float* __restrict__ b3,
                                               const float* __restrict__ dinv,
                                               float* __restrict__ h0,
                                               _Float16* __restrict__ hs0) {
    __shared__ char buf[32 * 512];  // 16 KB
    const int t = threadIdx.x;
    const int lane = t & 63;
    const int G = lane >> 4;
    const int w = t >> 6;
    const int T = blockIdx.x;

    half8v wr[8][2];
    {
        const half8v* W2f = reinterpret_cast<const half8v*>(Wf2);
#pragma unroll
        for (int kt = 0; kt < 8; kt++)
#pragma unroll
            for (int n2 = 0; n2 < 2; n2++)
                wr[kt][n2] = W2f[(kt * 16 + 2 * w + n2) * 64 + lane];
    }
    float bvs[2];
#pragma unroll
    for (int n2 = 0; n2 < 2; n2++) bvs[n2] = b2[w * 32 + n2 * 16 + (lane & 15)];

    // stage h1 image (pure 16B memcpy)
    {
        const half8v* srcp = reinterpret_cast<const half8v*>(h1g + (size_t)T * 8192);
        half8v* dst = reinterpret_cast<half8v*>(buf);
#pragma unroll
        for (int i = t; i < 1024; i += 512) dst[i] = srcp[i];
    }
    __syncthreads();

    // GEMM2
    f32x4 acc[2][2];
#pragma unroll
    for (int mt = 0; mt < 2; mt++)
#pragma unroll
        for (int n2 = 0; n2 < 2; n2++) acc[mt][n2] = (f32x4)0.f;
#pragma unroll
    for (int kt = 0; kt < 8; kt++) {
        half8v a[2];
#pragma unroll
        for (int mt = 0; mt < 2; mt++) {
            int row = mt * 16 + (lane & 15);
            int bo = (row * 512 + kt * 64 + (G << 4)) ^ ((row & 7) << 4);
            a[mt] = *reinterpret_cast<const half8v*>(buf + bo);
        }
#pragma unroll
        for (int mt = 0; mt < 2; mt++)
#pragma unroll
            for (int n2 = 0; n2 < 2; n2++)
                acc[mt][n2] = __builtin_amdgcn_mfma_f32_16x16x32_f16(a[mt], wr[kt][n2], acc[mt][n2], 0, 0, 0);
    }
    __syncthreads();

    // h2 -> LDS (swizzled fp16)
#pragma unroll
    for (int mt = 0; mt < 2; mt++)
#pragma unroll
        for (int n2 = 0; n2 < 2; n2++) {
            int colc = w * 32 + n2 * 16 + (lane & 15);
            float bb = bvs[n2];
#pragma unroll
            for (int r = 0; r < 4; r++) {
                int row = mt * 16 + G * 4 + r;
                float v = fmaxf(acc[mt][n2][r] + bb, 0.f);
                int bo = (row * 512 + colc * 2) ^ ((row & 7) << 4);
                *reinterpret_cast<_Float16*>(buf + bo) = (_Float16)v;
            }
        }
    __syncthreads();

    // GEMM3 on waves 0-3: wave -> (mt3 = w>>1 rows, ct3 = w&1 cols)
    if (w < 4) {
        const half8v* W3f = reinterpret_cast<const half8v*>(Wf3);
        const int mt3 = w >> 1, ct3 = w & 1;
        const float bb3 = b3[ct3 * 16 + (lane & 15)];
        f32x4 a3 = (f32x4)0.f;
#pragma unroll
        for (int kt = 0; kt < 8; kt++) {
            int row = mt3 * 16 + (lane & 15);
            int bo = (row * 512 + kt * 64 + (G << 4)) ^ ((row & 7) << 4);
            half8v a = *reinterpret_cast<const half8v*>(buf + bo);
            half8v b = W3f[(kt * 2 + ct3) * 64 + lane];
            a3 = __builtin_amdgcn_mfma_f32_16x16x32_f16(a, b, a3, 0, 0, 0);
        }
        int colc = ct3 * 16 + (lane & 15);
#pragma unroll
        for (int r = 0; r < 4; r++) {
            size_t row = (size_t)T * 32 + mt3 * 16 + G * 4 + r;
            float v = a3[r] + bb3;
            h0[row * 32 + colc] = v;
            hs0[row * 32 + colc] = (_Float16)(dinv[row] * v);
        }
    }
}

// ---------------- fused APPNP step (fp16 gather: 64B = 1 line per edge) ----------------

template<bool FINAL>
__global__ __launch_bounds__(256) void k_appnp(const int* __restrict__ begp,
                                               const int* __restrict__ endp,
                                               const int* __restrict__ col,
                                               const float* __restrict__ dinv,
                                               const _Float16* __restrict__ hs,
                                               const float* __restrict__ h0,
                                               void* __restrict__ outp) {
    int node = blockIdx.x * 8 + (threadIdx.x >> 5);
    if (node >= NN) return;
    int c = threadIdx.x & 31;
    int e = begp[node];
    const int end = endp[node];
    float a0 = 0.f, a1 = 0.f, a2 = 0.f, a3 = 0.f;
    for (; e + 4 <= end; e += 4) {
        int s0 = col[e], s1 = col[e + 1], s2 = col[e + 2], s3 = col[e + 3];
        a0 += (float)hs[(size_t)s0 * 32 + c];
        a1 += (float)hs[(size_t)s1 * 32 + c];
        a2 += (float)hs[(size_t)s2 * 32 + c];
        a3 += (float)hs[(size_t)s3 * 32 + c];
    }
    for (; e < end; e++) a0 += (float)hs[(size_t)col[e] * 32 + c];
    size_t off = (size_t)node * 32 + c;
    float dd = dinv[node];
    float hnew = 0.9f * dd * (((a0 + a1) + (a2 + a3)) + (float)hs[off]) + 0.1f * h0[off];
    if (FINAL) ((float*)outp)[off] = hnew;
    else       ((_Float16*)outp)[off] = (_Float16)(dd * hnew);
}

// ---------------- launch ----------------

extern "C" void kernel_launch(void* const* d_in, const int* in_sizes, int n_in,
                              void* d_out, int out_size, void* d_ws, size_t ws_size,
                              hipStream_t stream) {
    const float* x     = (const float*)d_in[0];
    const int*   ei    = (const int*)d_in[1];
    const float* W_in  = (const float*)d_in[2];
    const float* b_in  = (const float*)d_in[3];
    const float* W_h   = (const float*)d_in[4];
    const float* b_h   = (const float*)d_in[5];
    const float* W_out = (const float*)d_in[6];
    const float* b_out = (const float*)d_in[7];
    float* out = (float*)d_out;

    const int* srcv = ei;
    const int* dstv = ei + NE;

    char* ws = (char*)d_ws;
    float* h0      = (float*)ws;                                 // NN*32 f32
    _Float16* hs0  = (_Float16*)(h0 + (size_t)NN * 32);          // NN*32 f16
    _Float16* hs1  = hs0 + (size_t)NN * 32;                      // NN*32 f16
    float* dinv    = (float*)(hs1 + (size_t)NN * 32);            // NN
    _Float16* Wf_in  = (_Float16*)(dinv + NN);                   // 256*256
    _Float16* Wf_h   = Wf_in + 256 * 256;                        // 256*256
    _Float16* Wf_out = Wf_h + 256 * 256;                         // 256*32
    _Float16* h1g    = Wf_out + 256 * 32;                        // NN*256 f16 (tile images)
    int* histT = (int*)(h1g + (size_t)NN * 256);                 // NBUCK*NCHK
    int* cntb  = histT + (size_t)NBUCK * NCHK;                   // NBUCKP
    int* data  = cntb + NBUCKP;                                  // NBUCKP*CAP
    int* col   = data + (size_t)NBUCKP * CAP;                    // NBUCKP*CAP
    int* begp  = col + (size_t)NBUCKP * CAP;                     // NN
    int* endp  = begp + NN;                                      // NN

    // --- bucket partition + local counting sort -> CSR + dinv ---
    k_count<<<NCHK, 256, 0, stream>>>(dstv, histT);
    k_scanb<<<NBUCK, 256, 0, stream>>>(histT, cntb);
    k_part<<<NCHK, 256, 0, stream>>>(srcv, dstv, histT, data);
    k_sortb<<<NBUCK, 256, 0, stream>>>(data, cntb, col, begp, endp, dinv);

    // --- W fragments (one launch) ---
    k_wfrag_all<<<544, 256, 0, stream>>>(W_in, W_h, W_out, Wf_in, Wf_h, Wf_out);

    // --- MLP: 8-wave blocks, W slices register-resident (64 VGPR/wave) ---
    k_lay1<<<NTILE, 512, 0, stream>>>(x, Wf_in, b_in, h1g);
    k_lay23<<<NTILE, 512, 0, stream>>>(h1g, Wf_h, Wf_out, b_h, b_out, dinv, h0, hs0);

    // --- APPNP: K = 2 (fp16 gather) ---
    k_appnp<false><<<(NN + 7) / 8, 256, 0, stream>>>(begp, endp, col, dinv, hs0, h0, hs1);
    k_appnp<true ><<<(NN + 7) / 8, 256, 0, stream>>>(begp, endp, col, dinv, hs1, h0, out);
}

// Round 13
// 182.106 us; speedup vs baseline: 1.2885x; 1.0629x over previous
//
#include <hip/hip_runtime.h>

#define NN 100000
#define NE 1600000
#define NTILE 3125   // NN / 32

#define BSH 7
#define BNODES 128               // nodes per bucket
#define NBUCK 782                // ceil(NN / 128)
#define NBUCKP 784
#define CAP 2560                 // words per bucket region (exp 2048, +11 sigma)
#define ECH 2048                 // edges per chunk
#define NCHK 782                 // ceil(NE / ECH)

typedef _Float16 half8v __attribute__((ext_vector_type(8)));
typedef _Float16 half4v __attribute__((ext_vector_type(4)));
typedef float f32x4 __attribute__((ext_vector_type(4)));

// ---------------- bucket partition (no global atomics) ----------------

__global__ __launch_bounds__(256) void k_count(const int* __restrict__ dst,
                                               int* __restrict__ histT) {
    __shared__ int h[NBUCKP];
    const int t = threadIdx.x;
    for (int b = t; b < NBUCKP; b += 256) h[b] = 0;
    __syncthreads();
    const int ebase = blockIdx.x * ECH + t * 8;
#pragma unroll
    for (int q = 0; q < 2; q++) {
        int e = ebase + q * 4;
        if (e + 4 <= NE) {
            int4 d4 = *reinterpret_cast<const int4*>(dst + e);
            atomicAdd(&h[d4.x >> BSH], 1);
            atomicAdd(&h[d4.y >> BSH], 1);
            atomicAdd(&h[d4.z >> BSH], 1);
            atomicAdd(&h[d4.w >> BSH], 1);
        } else {
            for (int p = e; p < NE; p++) atomicAdd(&h[dst[p] >> BSH], 1);
        }
    }
    __syncthreads();
    for (int b = t; b < NBUCK; b += 256) histT[(long long)b * NCHK + blockIdx.x] = h[b];
}

__global__ __launch_bounds__(256) void k_scanb(int* __restrict__ histT,
                                               int* __restrict__ cntb) {
    __shared__ int s[256];
    const int b = blockIdx.x, t = threadIdx.x;
    int* row = histT + (long long)b * NCHK;
    int v[4];
    int sum = 0;
#pragma unroll
    for (int j = 0; j < 4; j++) {
        int idx = t * 4 + j;
        v[j] = (idx < NCHK) ? row[idx] : 0;
        sum += v[j];
    }
    s[t] = sum;
    __syncthreads();
    for (int off = 1; off < 256; off <<= 1) {
        int u = (t >= off) ? s[t - off] : 0;
        __syncthreads();
        s[t] += u;
        __syncthreads();
    }
    int run = s[t] - sum;
#pragma unroll
    for (int j = 0; j < 4; j++) {
        int idx = t * 4 + j;
        if (idx < NCHK) row[idx] = run;
        run += v[j];
    }
    if (t == 255) cntb[b] = s[255];
}

__global__ __launch_bounds__(256) void k_part(const int* __restrict__ src,
                                              const int* __restrict__ dst,
                                              const int* __restrict__ histT,
                                              int* __restrict__ data) {
    __shared__ int curs[NBUCKP];
    const int t = threadIdx.x, blk = blockIdx.x;
    for (int b = t; b < NBUCKP; b += 256)
        curs[b] = b * CAP + ((b < NBUCK) ? histT[(long long)b * NCHK + blk] : 0);
    __syncthreads();
    const int ebase = blk * ECH + t * 8;
#pragma unroll
    for (int q = 0; q < 2; q++) {
        int e = ebase + q * 4;
        if (e + 4 <= NE) {
            int4 d4 = *reinterpret_cast<const int4*>(dst + e);
            int4 s4 = *reinterpret_cast<const int4*>(src + e);
            int p0 = atomicAdd(&curs[d4.x >> BSH], 1);
            data[p0] = (s4.x << BSH) | (d4.x & (BNODES - 1));
            int p1 = atomicAdd(&curs[d4.y >> BSH], 1);
            data[p1] = (s4.y << BSH) | (d4.y & (BNODES - 1));
            int p2 = atomicAdd(&curs[d4.z >> BSH], 1);
            data[p2] = (s4.z << BSH) | (d4.z & (BNODES - 1));
            int p3 = atomicAdd(&curs[d4.w >> BSH], 1);
            data[p3] = (s4.w << BSH) | (d4.w & (BNODES - 1));
        } else {
            for (int p = e; p < NE; p++) {
                int d = dst[p], sv = src[p];
                int pos = atomicAdd(&curs[d >> BSH], 1);
                data[pos] = (sv << BSH) | (d & (BNODES - 1));
            }
        }
    }
}

// per-bucket LDS counting sort -> dst-ordered col[] + beg/end + dinv.
__global__ __launch_bounds__(256) void k_sortb(const int* __restrict__ data,
                                               const int* __restrict__ cntb,
                                               int* __restrict__ col,
                                               int* __restrict__ begp,
                                               int* __restrict__ endp,
                                               float* __restrict__ dinv) {
    __shared__ int hist[BNODES];
    __shared__ int scn[BNODES];
    __shared__ int curs[BNODES];
    const int b = blockIdx.x, t = threadIdx.x;
    if (t < BNODES) hist[t] = 0;
    __syncthreads();
    const int cnt = cntb[b];
    const int* wp = data + b * CAP;
    for (int e = t; e < cnt; e += 256) atomicAdd(&hist[wp[e] & (BNODES - 1)], 1);
    __syncthreads();
    if (t < BNODES) scn[t] = hist[t];
    __syncthreads();
    for (int off = 1; off < BNODES; off <<= 1) {
        int v = (t < BNODES && t >= off) ? scn[t - off] : 0;
        __syncthreads();
        if (t < BNODES) scn[t] += v;
        __syncthreads();
    }
    if (t < BNODES) {
        int beg = scn[t] - hist[t];
        curs[t] = beg;
        int node = (b << BSH) + t;
        if (node < NN) {
            begp[node] = b * CAP + beg;
            endp[node] = b * CAP + scn[t];
            dinv[node] = rsqrtf((float)(hist[t] + 1));
        }
    }
    __syncthreads();
    for (int e = t; e < cnt; e += 256) {
        int w = wp[e];
        int p = atomicAdd(&curs[w & (BNODES - 1)], 1);
        col[b * CAP + p] = w >> BSH;
    }
}

// ---------------- W -> fp16 B-fragment layout (all three, one launch) ----------------
// Wf[((kt*(N/16)+nt)*64 + l)*8 + j] = W[(kt*32 + (l>>4)*8 + j)*N + nt*16 + (l&15)]

__device__ __forceinline__ void wfrag_one(const float* __restrict__ W,
                                          _Float16* __restrict__ Wf, int idx, int N) {
    int j = idx & 7;
    int l = (idx >> 3) & 63;
    int f = idx >> 9;
    int nt = f % (N / 16);
    int kt = f / (N / 16);
    int k = kt * 32 + (l >> 4) * 8 + j;
    int c = nt * 16 + (l & 15);
    Wf[idx] = (_Float16)W[k * N + c];
}

__global__ __launch_bounds__(256) void k_wfrag_all(const float* __restrict__ W1,
                                                   const float* __restrict__ W2,
                                                   const float* __restrict__ W3,
                                                   _Float16* __restrict__ Wf1,
                                                   _Float16* __restrict__ Wf2,
                                                   _Float16* __restrict__ Wf3) {
    int idx = blockIdx.x * 256 + threadIdx.x;
    if (idx < 65536) wfrag_one(W1, Wf1, idx, 256);
    else if (idx < 131072) wfrag_one(W2, Wf2, idx - 65536, 256);
    else if (idx < 139264) wfrag_one(W3, Wf3, idx - 131072, 32);
}

// ---------------- Layer 1: x -> h1 (raw swizzled 16KB tile images) ----------------

__global__ __launch_bounds__(512) void k_lay1(const float* __restrict__ x,
                                              const _Float16* __restrict__ Wf1,
                                              const float* __restrict__ b1,
                                              _Float16* __restrict__ h1g) {
    __shared__ char buf[32 * 512];  // 16 KB
    const int t = threadIdx.x;
    const int lane = t & 63;
    const int G = lane >> 4;
    const int w = t >> 6;
    const int T = blockIdx.x;

    half8v wr[8][2];
    {
        const half8v* W1f = reinterpret_cast<const half8v*>(Wf1);
#pragma unroll
        for (int kt = 0; kt < 8; kt++)
#pragma unroll
            for (int n2 = 0; n2 < 2; n2++)
                wr[kt][n2] = W1f[(kt * 16 + 2 * w + n2) * 64 + lane];
    }
    float bvs[2];
#pragma unroll
    for (int n2 = 0; n2 < 2; n2++) bvs[n2] = b1[w * 32 + n2 * 16 + (lane & 15)];

    {
        const float4* A4 = reinterpret_cast<const float4*>(x + (size_t)T * 32 * 256);
#pragma unroll
        for (int i = t; i < 2048; i += 512) {
            int r = i >> 6, c4 = i & 63;
            float4 v = A4[i];
            half4v hv;
            hv[0] = (_Float16)v.x; hv[1] = (_Float16)v.y;
            hv[2] = (_Float16)v.z; hv[3] = (_Float16)v.w;
            int bo = (r * 512 + c4 * 8) ^ ((r & 7) << 4);
            *reinterpret_cast<half4v*>(buf + bo) = hv;
        }
    }
    __syncthreads();

    f32x4 acc[2][2];
#pragma unroll
    for (int mt = 0; mt < 2; mt++)
#pragma unroll
        for (int n2 = 0; n2 < 2; n2++) acc[mt][n2] = (f32x4)0.f;
#pragma unroll
    for (int kt = 0; kt < 8; kt++) {
        half8v a[2];
#pragma unroll
        for (int mt = 0; mt < 2; mt++) {
            int row = mt * 16 + (lane & 15);
            int bo = (row * 512 + kt * 64 + (G << 4)) ^ ((row & 7) << 4);
            a[mt] = *reinterpret_cast<const half8v*>(buf + bo);
        }
#pragma unroll
        for (int mt = 0; mt < 2; mt++)
#pragma unroll
            for (int n2 = 0; n2 < 2; n2++)
                acc[mt][n2] = __builtin_amdgcn_mfma_f32_16x16x32_f16(a[mt], wr[kt][n2], acc[mt][n2], 0, 0, 0);
    }
    __syncthreads();

#pragma unroll
    for (int mt = 0; mt < 2; mt++)
#pragma unroll
        for (int n2 = 0; n2 < 2; n2++) {
            int colc = w * 32 + n2 * 16 + (lane & 15);
            float bb = bvs[n2];
#pragma unroll
            for (int r = 0; r < 4; r++) {
                int row = mt * 16 + G * 4 + r;
                float v = fmaxf(acc[mt][n2][r] + bb, 0.f);
                int bo = (row * 512 + colc * 2) ^ ((row & 7) << 4);
                *reinterpret_cast<_Float16*>(buf + bo) = (_Float16)v;
            }
        }
    __syncthreads();

    {
        half8v* dst = reinterpret_cast<half8v*>(h1g + (size_t)T * 8192);
        const half8v* srcp = reinterpret_cast<const half8v*>(buf);
#pragma unroll
        for (int i = t; i < 1024; i += 512) dst[i] = srcp[i];
    }
}

// ---------------- Layers 2+3: h1 image -> h0f (f16), hs0 (f16) ----------------

__global__ __launch_bounds__(512) void k_lay23(const _Float16* __restrict__ h1g,
                                               const _Float16* __restrict__ Wf2,
                                               const _Float16* __restrict__ Wf3,
                                               const float* __restrict__ b2,
                                               const float* __restrict__ b3,
                                               const float* __restrict__ dinv,
                                               _Float16* __restrict__ h0f,
                                               _Float16* __restrict__ hs0) {
    __shared__ char buf[32 * 512];  // 16 KB
    const int t = threadIdx.x;
    const int lane = t & 63;
    const int G = lane >> 4;
    const int w = t >> 6;
    const int T = blockIdx.x;

    half8v wr[8][2];
    {
        const half8v* W2f = reinterpret_cast<const half8v*>(Wf2);
#pragma unroll
        for (int kt = 0; kt < 8; kt++)
#pragma unroll
            for (int n2 = 0; n2 < 2; n2++)
                wr[kt][n2] = W2f[(kt * 16 + 2 * w + n2) * 64 + lane];
    }
    float bvs[2];
#pragma unroll
    for (int n2 = 0; n2 < 2; n2++) bvs[n2] = b2[w * 32 + n2 * 16 + (lane & 15)];

    {
        const half8v* srcp = reinterpret_cast<const half8v*>(h1g + (size_t)T * 8192);
        half8v* dst = reinterpret_cast<half8v*>(buf);
#pragma unroll
        for (int i = t; i < 1024; i += 512) dst[i] = srcp[i];
    }
    __syncthreads();

    f32x4 acc[2][2];
#pragma unroll
    for (int mt = 0; mt < 2; mt++)
#pragma unroll
        for (int n2 = 0; n2 < 2; n2++) acc[mt][n2] = (f32x4)0.f;
#pragma unroll
    for (int kt = 0; kt < 8; kt++) {
        half8v a[2];
#pragma unroll
        for (int mt = 0; mt < 2; mt++) {
            int row = mt * 16 + (lane & 15);
            int bo = (row * 512 + kt * 64 + (G << 4)) ^ ((row & 7) << 4);
            a[mt] = *reinterpret_cast<const half8v*>(buf + bo);
        }
#pragma unroll
        for (int mt = 0; mt < 2; mt++)
#pragma unroll
            for (int n2 = 0; n2 < 2; n2++)
                acc[mt][n2] = __builtin_amdgcn_mfma_f32_16x16x32_f16(a[mt], wr[kt][n2], acc[mt][n2], 0, 0, 0);
    }
    __syncthreads();

#pragma unroll
    for (int mt = 0; mt < 2; mt++)
#pragma unroll
        for (int n2 = 0; n2 < 2; n2++) {
            int colc = w * 32 + n2 * 16 + (lane & 15);
            float bb = bvs[n2];
#pragma unroll
            for (int r = 0; r < 4; r++) {
                int row = mt * 16 + G * 4 + r;
                float v = fmaxf(acc[mt][n2][r] + bb, 0.f);
                int bo = (row * 512 + colc * 2) ^ ((row & 7) << 4);
                *reinterpret_cast<_Float16*>(buf + bo) = (_Float16)v;
            }
        }
    __syncthreads();

    if (w < 4) {
        const half8v* W3f = reinterpret_cast<const half8v*>(Wf3);
        const int mt3 = w >> 1, ct3 = w & 1;
        const float bb3 = b3[ct3 * 16 + (lane & 15)];
        f32x4 a3 = (f32x4)0.f;
#pragma unroll
        for (int kt = 0; kt < 8; kt++) {
            int row = mt3 * 16 + (lane & 15);
            int bo = (row * 512 + kt * 64 + (G << 4)) ^ ((row & 7) << 4);
            half8v a = *reinterpret_cast<const half8v*>(buf + bo);
            half8v b = W3f[(kt * 2 + ct3) * 64 + lane];
            a3 = __builtin_amdgcn_mfma_f32_16x16x32_f16(a, b, a3, 0, 0, 0);
        }
        int colc = ct3 * 16 + (lane & 15);
#pragma unroll
        for (int r = 0; r < 4; r++) {
            size_t row = (size_t)T * 32 + mt3 * 16 + G * 4 + r;
            float v = a3[r] + bb3;
            h0f[row * 32 + colc] = (_Float16)v;
            hs0[row * 32 + colc] = (_Float16)(dinv[row] * v);
        }
    }
}

// ---------------- fused APPNP step: one wave per node, 16 edges in flight ----------------
// lane l: edge slot = l>>2, channel group cg = l&3 (8 fp16 ch = 16B/lane).
// Cross-slot reduce via 4 shfl_xor steps. Self + h0 issued early.

template<bool FINAL>
__global__ __launch_bounds__(256) void k_appnp(const int* __restrict__ begp,
                                               const int* __restrict__ endp,
                                               const int* __restrict__ col,
                                               const float* __restrict__ dinv,
                                               const _Float16* __restrict__ hs,
                                               const _Float16* __restrict__ h0f,
                                               void* __restrict__ outp) {
    int node = blockIdx.x * 4 + (threadIdx.x >> 6);
    if (node >= NN) return;
    const int lane = threadIdx.x & 63;
    const int slot = lane >> 2;
    const int cg = lane & 3;

    const int beg = begp[node];
    const int end = endp[node];
    const float dd = dinv[node];
    const half8v selfv = *reinterpret_cast<const half8v*>(hs + (size_t)node * 32 + cg * 8);
    const half8v h0v = *reinterpret_cast<const half8v*>(h0f + (size_t)node * 32 + cg * 8);

    float acc[8];
#pragma unroll
    for (int j = 0; j < 8; j++) acc[j] = 0.f;

    for (int e = beg + slot; e < end; e += 16) {
        int s = col[e];
        half8v v = *reinterpret_cast<const half8v*>(hs + (size_t)s * 32 + cg * 8);
#pragma unroll
        for (int j = 0; j < 8; j++) acc[j] += (float)v[j];
    }

    // reduce over the 16 slots (lanes stride 4)
#pragma unroll
    for (int off = 4; off < 64; off <<= 1) {
#pragma unroll
        for (int j = 0; j < 8; j++) acc[j] += __shfl_xor(acc[j], off, 64);
    }

    if (slot == 0) {
        float o[8];
#pragma unroll
        for (int j = 0; j < 8; j++)
            o[j] = 0.9f * dd * (acc[j] + (float)selfv[j]) + 0.1f * (float)h0v[j];
        size_t off = (size_t)node * 32 + cg * 8;
        if (FINAL) {
            float4 v0 = make_float4(o[0], o[1], o[2], o[3]);
            float4 v1 = make_float4(o[4], o[5], o[6], o[7]);
            float4* op = reinterpret_cast<float4*>((float*)outp + off);
            op[0] = v0; op[1] = v1;
        } else {
            half8v hv;
#pragma unroll
            for (int j = 0; j < 8; j++) hv[j] = (_Float16)(dd * o[j]);
            *reinterpret_cast<half8v*>((_Float16*)outp + off) = hv;
        }
    }
}

// ---------------- launch ----------------

extern "C" void kernel_launch(void* const* d_in, const int* in_sizes, int n_in,
                              void* d_out, int out_size, void* d_ws, size_t ws_size,
                              hipStream_t stream) {
    const float* x     = (const float*)d_in[0];
    const int*   ei    = (const int*)d_in[1];
    const float* W_in  = (const float*)d_in[2];
    const float* b_in  = (const float*)d_in[3];
    const float* W_h   = (const float*)d_in[4];
    const float* b_h   = (const float*)d_in[5];
    const float* W_out = (const float*)d_in[6];
    const float* b_out = (const float*)d_in[7];
    float* out = (float*)d_out;

    const int* srcv = ei;
    const int* dstv = ei + NE;

    char* ws = (char*)d_ws;
    _Float16* h0f  = (_Float16*)ws;                              // NN*32 f16
    _Float16* hs0  = h0f + (size_t)NN * 32;                      // NN*32 f16
    _Float16* hs1  = hs0 + (size_t)NN * 32;                      // NN*32 f16
    float* dinv    = (float*)(hs1 + (size_t)NN * 32);            // NN
    _Float16* Wf_in  = (_Float16*)(dinv + NN);                   // 256*256
    _Float16* Wf_h   = Wf_in + 256 * 256;                        // 256*256
    _Float16* Wf_out = Wf_h + 256 * 256;                         // 256*32
    _Float16* h1g    = Wf_out + 256 * 32;                        // NN*256 f16 (tile images)
    int* histT = (int*)(h1g + (size_t)NN * 256);                 // NBUCK*NCHK
    int* cntb  = histT + (size_t)NBUCK * NCHK;                   // NBUCKP
    int* data  = cntb + NBUCKP;                                  // NBUCKP*CAP
    int* col   = data + (size_t)NBUCKP * CAP;                    // NBUCKP*CAP
    int* begp  = col + (size_t)NBUCKP * CAP;                     // NN
    int* endp  = begp + NN;                                      // NN

    // --- bucket partition + local counting sort -> CSR + dinv ---
    k_count<<<NCHK, 256, 0, stream>>>(dstv, histT);
    k_scanb<<<NBUCK, 256, 0, stream>>>(histT, cntb);
    k_part<<<NCHK, 256, 0, stream>>>(srcv, dstv, histT, data);
    k_sortb<<<NBUCK, 256, 0, stream>>>(data, cntb, col, begp, endp, dinv);

    // --- W fragments (one launch) ---
    k_wfrag_all<<<544, 256, 0, stream>>>(W_in, W_h, W_out, Wf_in, Wf_h, Wf_out);

    // --- MLP: 8-wave blocks, W slices register-resident ---
    k_lay1<<<NTILE, 512, 0, stream>>>(x, Wf_in, b_in, h1g);
    k_lay23<<<NTILE, 512, 0, stream>>>(h1g, Wf_h, Wf_out, b_h, b_out, dinv, h0f, hs0);

    // --- APPNP: K = 2 (wave-per-node, 16-wide gather) ---
    k_appnp<false><<<(NN + 3) / 4, 256, 0, stream>>>(begp, endp, col, dinv, hs0, h0f, hs1);
    k_appnp<true ><<<(NN + 3) / 4, 256, 0, stream>>>(begp, endp, col, dinv, hs1, h0f, out);
}

// Round 14
// 166.138 us; speedup vs baseline: 1.4123x; 1.0961x over previous
//
#include <hip/hip_runtime.h>

#define NN 100000
#define NE 1600000
#define NTILE 3125   // NN / 32

#define BSH 7
#define BNODES 128               // nodes per bucket
#define NBUCK 782                // ceil(NN / 128)
#define NBUCKP 784
#define CAP 2560                 // words per bucket region (exp 2048, +11 sigma)
#define ECH 8192                 // edges per chunk
#define NCHK 196                 // ceil(NE / ECH)
#define WFRAG_BLKS 272           // 139264 / 512

typedef _Float16 half8v __attribute__((ext_vector_type(8)));
typedef _Float16 half4v __attribute__((ext_vector_type(4)));
typedef float f32x4 __attribute__((ext_vector_type(4)));

// ---------------- W -> fp16 B-fragment layout ----------------
// Wf[((kt*(N/16)+nt)*64 + l)*8 + j] = W[(kt*32 + (l>>4)*8 + j)*N + nt*16 + (l&15)]

__device__ __forceinline__ void wfrag_one(const float* __restrict__ W,
                                          _Float16* __restrict__ Wf, int idx, int N) {
    int j = idx & 7;
    int l = (idx >> 3) & 63;
    int f = idx >> 9;
    int nt = f % (N / 16);
    int kt = f / (N / 16);
    int k = kt * 32 + (l >> 4) * 8 + j;
    int c = nt * 16 + (l & 15);
    Wf[idx] = (_Float16)W[k * N + c];
}

// ---------------- merged: bucket count (blocks 0..195) | wfrag (196..467) ----------------

__global__ __launch_bounds__(512) void k_count_wfrag(const int* __restrict__ dst,
                                                     int* __restrict__ histT,
                                                     const float* __restrict__ W1,
                                                     const float* __restrict__ W2,
                                                     const float* __restrict__ W3,
                                                     _Float16* __restrict__ Wf1,
                                                     _Float16* __restrict__ Wf2,
                                                     _Float16* __restrict__ Wf3) {
    const int t = threadIdx.x;
    if (blockIdx.x >= NCHK) {
        int idx = (blockIdx.x - NCHK) * 512 + t;
        if (idx < 65536) wfrag_one(W1, Wf1, idx, 256);
        else if (idx < 131072) wfrag_one(W2, Wf2, idx - 65536, 256);
        else if (idx < 139264) wfrag_one(W3, Wf3, idx - 131072, 32);
        return;
    }
    __shared__ int h[NBUCKP];
    const int blk = blockIdx.x;
    for (int b = t; b < NBUCKP; b += 512) h[b] = 0;
    __syncthreads();
    const int ebase = blk * ECH + t * 16;
#pragma unroll
    for (int q = 0; q < 4; q++) {
        int e = ebase + q * 4;
        if (e + 4 <= NE) {
            int4 d4 = *reinterpret_cast<const int4*>(dst + e);
            atomicAdd(&h[d4.x >> BSH], 1);
            atomicAdd(&h[d4.y >> BSH], 1);
            atomicAdd(&h[d4.z >> BSH], 1);
            atomicAdd(&h[d4.w >> BSH], 1);
        } else {
            for (int p = e; p < NE; p++) atomicAdd(&h[dst[p] >> BSH], 1);
            break;
        }
    }
    __syncthreads();
    for (int b = t; b < NBUCK; b += 512) histT[(long long)b * NCHK + blk] = h[b];
}

// ---------------- per-bucket exclusive scan over chunks ----------------

__global__ __launch_bounds__(256) void k_scanb(int* __restrict__ histT,
                                               int* __restrict__ cntb) {
    __shared__ int s[256];
    const int b = blockIdx.x, t = threadIdx.x;
    int* row = histT + (long long)b * NCHK;
    int v = (t < NCHK) ? row[t] : 0;
    s[t] = v;
    __syncthreads();
    for (int off = 1; off < 256; off <<= 1) {
        int u = (t >= off) ? s[t - off] : 0;
        __syncthreads();
        s[t] += u;
        __syncthreads();
    }
    if (t < NCHK) row[t] = s[t] - v;
    if (t == 255) cntb[b] = s[255];
}

// ---------------- merged: part scatter (blocks 0..195) | layer1 (196..3320) ----------------

__global__ __launch_bounds__(512) void k_part_lay1(const int* __restrict__ src,
                                                   const int* __restrict__ dst,
                                                   const int* __restrict__ histT,
                                                   int* __restrict__ data,
                                                   const float* __restrict__ x,
                                                   const _Float16* __restrict__ Wf1,
                                                   const float* __restrict__ b1,
                                                   _Float16* __restrict__ h1g) {
    __shared__ char smem[16384];
    const int t = threadIdx.x;

    if (blockIdx.x < NCHK) {
        // ---- bucket partition scatter ----
        int* curs = (int*)smem;
        const int blk = blockIdx.x;
        for (int b = t; b < NBUCKP; b += 512)
            curs[b] = b * CAP + ((b < NBUCK) ? histT[(long long)b * NCHK + blk] : 0);
        __syncthreads();
        const int ebase = blk * ECH + t * 16;
#pragma unroll
        for (int q = 0; q < 4; q++) {
            int e = ebase + q * 4;
            if (e + 4 <= NE) {
                int4 d4 = *reinterpret_cast<const int4*>(dst + e);
                int4 s4 = *reinterpret_cast<const int4*>(src + e);
                int p0 = atomicAdd(&curs[d4.x >> BSH], 1);
                data[p0] = (s4.x << BSH) | (d4.x & (BNODES - 1));
                int p1 = atomicAdd(&curs[d4.y >> BSH], 1);
                data[p1] = (s4.y << BSH) | (d4.y & (BNODES - 1));
                int p2 = atomicAdd(&curs[d4.z >> BSH], 1);
                data[p2] = (s4.z << BSH) | (d4.z & (BNODES - 1));
                int p3 = atomicAdd(&curs[d4.w >> BSH], 1);
                data[p3] = (s4.w << BSH) | (d4.w & (BNODES - 1));
            } else {
                for (int p = e; p < NE; p++) {
                    int d = dst[p], sv = src[p];
                    int pos = atomicAdd(&curs[d >> BSH], 1);
                    data[pos] = (sv << BSH) | (d & (BNODES - 1));
                }
                break;
            }
        }
        return;
    }

    // ---- layer 1: x -> h1 (raw swizzled 16KB tile images) ----
    char* buf = smem;
    const int lane = t & 63;
    const int G = lane >> 4;
    const int w = t >> 6;
    const int T = blockIdx.x - NCHK;

    half8v wr[8][2];
    {
        const half8v* W1f = reinterpret_cast<const half8v*>(Wf1);
#pragma unroll
        for (int kt = 0; kt < 8; kt++)
#pragma unroll
            for (int n2 = 0; n2 < 2; n2++)
                wr[kt][n2] = W1f[(kt * 16 + 2 * w + n2) * 64 + lane];
    }
    float bvs[2];
#pragma unroll
    for (int n2 = 0; n2 < 2; n2++) bvs[n2] = b1[w * 32 + n2 * 16 + (lane & 15)];

    {
        const float4* A4 = reinterpret_cast<const float4*>(x + (size_t)T * 32 * 256);
#pragma unroll
        for (int i = t; i < 2048; i += 512) {
            int r = i >> 6, c4 = i & 63;
            float4 v = A4[i];
            half4v hv;
            hv[0] = (_Float16)v.x; hv[1] = (_Float16)v.y;
            hv[2] = (_Float16)v.z; hv[3] = (_Float16)v.w;
            int bo = (r * 512 + c4 * 8) ^ ((r & 7) << 4);
            *reinterpret_cast<half4v*>(buf + bo) = hv;
        }
    }
    __syncthreads();

    f32x4 acc[2][2];
#pragma unroll
    for (int mt = 0; mt < 2; mt++)
#pragma unroll
        for (int n2 = 0; n2 < 2; n2++) acc[mt][n2] = (f32x4)0.f;
#pragma unroll
    for (int kt = 0; kt < 8; kt++) {
        half8v a[2];
#pragma unroll
        for (int mt = 0; mt < 2; mt++) {
            int row = mt * 16 + (lane & 15);
            int bo = (row * 512 + kt * 64 + (G << 4)) ^ ((row & 7) << 4);
            a[mt] = *reinterpret_cast<const half8v*>(buf + bo);
        }
#pragma unroll
        for (int mt = 0; mt < 2; mt++)
#pragma unroll
            for (int n2 = 0; n2 < 2; n2++)
                acc[mt][n2] = __builtin_amdgcn_mfma_f32_16x16x32_f16(a[mt], wr[kt][n2], acc[mt][n2], 0, 0, 0);
    }
    __syncthreads();

#pragma unroll
    for (int mt = 0; mt < 2; mt++)
#pragma unroll
        for (int n2 = 0; n2 < 2; n2++) {
            int colc = w * 32 + n2 * 16 + (lane & 15);
            float bb = bvs[n2];
#pragma unroll
            for (int r = 0; r < 4; r++) {
                int row = mt * 16 + G * 4 + r;
                float v = fmaxf(acc[mt][n2][r] + bb, 0.f);
                int bo = (row * 512 + colc * 2) ^ ((row & 7) << 4);
                *reinterpret_cast<_Float16*>(buf + bo) = (_Float16)v;
            }
        }
    __syncthreads();

    {
        half8v* dstp = reinterpret_cast<half8v*>(h1g + (size_t)T * 8192);
        const half8v* srcp = reinterpret_cast<const half8v*>(buf);
#pragma unroll
        for (int i = t; i < 1024; i += 512) dstp[i] = srcp[i];
    }
}

// ---------------- per-bucket LDS counting sort -> CSR + dinv ----------------

__global__ __launch_bounds__(256) void k_sortb(const int* __restrict__ data,
                                               const int* __restrict__ cntb,
                                               int* __restrict__ col,
                                               int* __restrict__ begp,
                                               int* __restrict__ endp,
                                               float* __restrict__ dinv) {
    __shared__ int hist[BNODES];
    __shared__ int scn[BNODES];
    __shared__ int curs[BNODES];
    const int b = blockIdx.x, t = threadIdx.x;
    if (t < BNODES) hist[t] = 0;
    __syncthreads();
    const int cnt = cntb[b];
    const int* wp = data + b * CAP;
    for (int e = t; e < cnt; e += 256) atomicAdd(&hist[wp[e] & (BNODES - 1)], 1);
    __syncthreads();
    if (t < BNODES) scn[t] = hist[t];
    __syncthreads();
    for (int off = 1; off < BNODES; off <<= 1) {
        int v = (t < BNODES && t >= off) ? scn[t - off] : 0;
        __syncthreads();
        if (t < BNODES) scn[t] += v;
        __syncthreads();
    }
    if (t < BNODES) {
        int beg = scn[t] - hist[t];
        curs[t] = beg;
        int node = (b << BSH) + t;
        if (node < NN) {
            begp[node] = b * CAP + beg;
            endp[node] = b * CAP + scn[t];
            dinv[node] = rsqrtf((float)(hist[t] + 1));
        }
    }
    __syncthreads();
    for (int e = t; e < cnt; e += 256) {
        int w = wp[e];
        int p = atomicAdd(&curs[w & (BNODES - 1)], 1);
        col[b * CAP + p] = w >> BSH;
    }
}

// ---------------- Layers 2+3: h1 image -> h0f (f16), hs0 (f16) ----------------

__global__ __launch_bounds__(512) void k_lay23(const _Float16* __restrict__ h1g,
                                               const _Float16* __restrict__ Wf2,
                                               const _Float16* __restrict__ Wf3,
                                               const float* __restrict__ b2,
                                               const float* __restrict__ b3,
                                               const float* __restrict__ dinv,
                                               _Float16* __restrict__ h0f,
                                               _Float16* __restrict__ hs0) {
    __shared__ char buf[32 * 512];  // 16 KB
    const int t = threadIdx.x;
    const int lane = t & 63;
    const int G = lane >> 4;
    const int w = t >> 6;
    const int T = blockIdx.x;

    half8v wr[8][2];
    {
        const half8v* W2f = reinterpret_cast<const half8v*>(Wf2);
#pragma unroll
        for (int kt = 0; kt < 8; kt++)
#pragma unroll
            for (int n2 = 0; n2 < 2; n2++)
                wr[kt][n2] = W2f[(kt * 16 + 2 * w + n2) * 64 + lane];
    }
    float bvs[2];
#pragma unroll
    for (int n2 = 0; n2 < 2; n2++) bvs[n2] = b2[w * 32 + n2 * 16 + (lane & 15)];

    {
        const half8v* srcp = reinterpret_cast<const half8v*>(h1g + (size_t)T * 8192);
        half8v* dstp = reinterpret_cast<half8v*>(buf);
#pragma unroll
        for (int i = t; i < 1024; i += 512) dstp[i] = srcp[i];
    }
    __syncthreads();

    f32x4 acc[2][2];
#pragma unroll
    for (int mt = 0; mt < 2; mt++)
#pragma unroll
        for (int n2 = 0; n2 < 2; n2++) acc[mt][n2] = (f32x4)0.f;
#pragma unroll
    for (int kt = 0; kt < 8; kt++) {
        half8v a[2];
#pragma unroll
        for (int mt = 0; mt < 2; mt++) {
            int row = mt * 16 + (lane & 15);
            int bo = (row * 512 + kt * 64 + (G << 4)) ^ ((row & 7) << 4);
            a[mt] = *reinterpret_cast<const half8v*>(buf + bo);
        }
#pragma unroll
        for (int mt = 0; mt < 2; mt++)
#pragma unroll
            for (int n2 = 0; n2 < 2; n2++)
                acc[mt][n2] = __builtin_amdgcn_mfma_f32_16x16x32_f16(a[mt], wr[kt][n2], acc[mt][n2], 0, 0, 0);
    }
    __syncthreads();

#pragma unroll
    for (int mt = 0; mt < 2; mt++)
#pragma unroll
        for (int n2 = 0; n2 < 2; n2++) {
            int colc = w * 32 + n2 * 16 + (lane & 15);
            float bb = bvs[n2];
#pragma unroll
            for (int r = 0; r < 4; r++) {
                int row = mt * 16 + G * 4 + r;
                float v = fmaxf(acc[mt][n2][r] + bb, 0.f);
                int bo = (row * 512 + colc * 2) ^ ((row & 7) << 4);
                *reinterpret_cast<_Float16*>(buf + bo) = (_Float16)v;
            }
        }
    __syncthreads();

    if (w < 4) {
        const half8v* W3f = reinterpret_cast<const half8v*>(Wf3);
        const int mt3 = w >> 1, ct3 = w & 1;
        const float bb3 = b3[ct3 * 16 + (lane & 15)];
        f32x4 a3 = (f32x4)0.f;
#pragma unroll
        for (int kt = 0; kt < 8; kt++) {
            int row = mt3 * 16 + (lane & 15);
            int bo = (row * 512 + kt * 64 + (G << 4)) ^ ((row & 7) << 4);
            half8v a = *reinterpret_cast<const half8v*>(buf + bo);
            half8v b = W3f[(kt * 2 + ct3) * 64 + lane];
            a3 = __builtin_amdgcn_mfma_f32_16x16x32_f16(a, b, a3, 0, 0, 0);
        }
        int colc = ct3 * 16 + (lane & 15);
#pragma unroll
        for (int r = 0; r < 4; r++) {
            size_t row = (size_t)T * 32 + mt3 * 16 + G * 4 + r;
            float v = a3[r] + bb3;
            h0f[row * 32 + colc] = (_Float16)v;
            hs0[row * 32 + colc] = (_Float16)(dinv[row] * v);
        }
    }
}

// ---------------- fused APPNP step: one wave per node, 16 edges in flight ----------------

template<bool FINAL>
__global__ __launch_bounds__(256) void k_appnp(const int* __restrict__ begp,
                                               const int* __restrict__ endp,
                                               const int* __restrict__ col,
                                               const float* __restrict__ dinv,
                                               const _Float16* __restrict__ hs,
                                               const _Float16* __restrict__ h0f,
                                               void* __restrict__ outp) {
    int node = blockIdx.x * 4 + (threadIdx.x >> 6);
    if (node >= NN) return;
    const int lane = threadIdx.x & 63;
    const int slot = lane >> 2;
    const int cg = lane & 3;

    const int beg = begp[node];
    const int end = endp[node];
    const float dd = dinv[node];
    const half8v selfv = *reinterpret_cast<const half8v*>(hs + (size_t)node * 32 + cg * 8);
    const half8v h0v = *reinterpret_cast<const half8v*>(h0f + (size_t)node * 32 + cg * 8);

    float acc[8];
#pragma unroll
    for (int j = 0; j < 8; j++) acc[j] = 0.f;

    for (int e = beg + slot; e < end; e += 16) {
        int s = col[e];
        half8v v = *reinterpret_cast<const half8v*>(hs + (size_t)s * 32 + cg * 8);
#pragma unroll
        for (int j = 0; j < 8; j++) acc[j] += (float)v[j];
    }

#pragma unroll
    for (int off = 4; off < 64; off <<= 1) {
#pragma unroll
        for (int j = 0; j < 8; j++) acc[j] += __shfl_xor(acc[j], off, 64);
    }

    if (slot == 0) {
        float o[8];
#pragma unroll
        for (int j = 0; j < 8; j++)
            o[j] = 0.9f * dd * (acc[j] + (float)selfv[j]) + 0.1f * (float)h0v[j];
        size_t off = (size_t)node * 32 + cg * 8;
        if (FINAL) {
            float4 v0 = make_float4(o[0], o[1], o[2], o[3]);
            float4 v1 = make_float4(o[4], o[5], o[6], o[7]);
            float4* op = reinterpret_cast<float4*>((float*)outp + off);
            op[0] = v0; op[1] = v1;
        } else {
            half8v hv;
#pragma unroll
            for (int j = 0; j < 8; j++) hv[j] = (_Float16)(dd * o[j]);
            *reinterpret_cast<half8v*>((_Float16*)outp + off) = hv;
        }
    }
}

// ---------------- launch ----------------

extern "C" void kernel_launch(void* const* d_in, const int* in_sizes, int n_in,
                              void* d_out, int out_size, void* d_ws, size_t ws_size,
                              hipStream_t stream) {
    const float* x     = (const float*)d_in[0];
    const int*   ei    = (const int*)d_in[1];
    const float* W_in  = (const float*)d_in[2];
    const float* b_in  = (const float*)d_in[3];
    const float* W_h   = (const float*)d_in[4];
    const float* b_h   = (const float*)d_in[5];
    const float* W_out = (const float*)d_in[6];
    const float* b_out = (const float*)d_in[7];
    float* out = (float*)d_out;

    const int* srcv = ei;
    const int* dstv = ei + NE;

    char* ws = (char*)d_ws;
    _Float16* h0f  = (_Float16*)ws;                              // NN*32 f16
    _Float16* hs0  = h0f + (size_t)NN * 32;                      // NN*32 f16
    _Float16* hs1  = hs0 + (size_t)NN * 32;                      // NN*32 f16
    float* dinv    = (float*)(hs1 + (size_t)NN * 32);            // NN
    _Float16* Wf_in  = (_Float16*)(dinv + NN);                   // 256*256
    _Float16* Wf_h   = Wf_in + 256 * 256;                        // 256*256
    _Float16* Wf_out = Wf_h + 256 * 256;                         // 256*32
    _Float16* h1g    = Wf_out + 256 * 32;                        // NN*256 f16 (tile images)
    int* histT = (int*)(h1g + (size_t)NN * 256);                 // NBUCK*NCHK
    int* cntb  = histT + (size_t)NBUCK * NCHK;                   // NBUCKP
    int* data  = cntb + NBUCKP;                                  // NBUCKP*CAP
    int* col   = data + (size_t)NBUCKP * CAP;                    // NBUCKP*CAP
    int* begp  = col + (size_t)NBUCKP * CAP;                     // NN
    int* endp  = begp + NN;                                      // NN

    // --- [bucket count | W fragments] ---
    k_count_wfrag<<<NCHK + WFRAG_BLKS, 512, 0, stream>>>(dstv, histT,
                                                         W_in, W_h, W_out,
                                                         Wf_in, Wf_h, Wf_out);
    // --- per-bucket scan ---
    k_scanb<<<NBUCK, 256, 0, stream>>>(histT, cntb);

    // --- [part scatter | layer 1] ---
    k_part_lay1<<<NCHK + NTILE, 512, 0, stream>>>(srcv, dstv, histT, data,
                                                  x, Wf_in, b_in, h1g);

    // --- per-bucket counting sort -> CSR + dinv ---
    k_sortb<<<NBUCK, 256, 0, stream>>>(data, cntb, col, begp, endp, dinv);

    // --- layers 2+3 ---
    k_lay23<<<NTILE, 512, 0, stream>>>(h1g, Wf_h, Wf_out, b_h, b_out, dinv, h0f, hs0);

    // --- APPNP: K = 2 (wave-per-node, 16-wide gather) ---
    k_appnp<false><<<(NN + 3) / 4, 256, 0, stream>>>(begp, endp, col, dinv, hs0, h0f, hs1);
    k_appnp<true ><<<(NN + 3) / 4, 256, 0, stream>>>(begp, endp, col, dinv, hs1, h0f, out);
}